// Round 2
// baseline (950.978 us; speedup 1.0000x reference)
//
#include <hip/hip_runtime.h>
#include <stdint.h>

// Window attention, Swin-style. B=4096 windows, N=49, C=256, NH=8, D=32.
// FULLY FUSED: one block per window (512 thr, 8 waves). x->bf16 in LDS,
// QKV GEMM (weights streamed from L2), per-head attention, proj GEMM,
// all intermediates in LDS. HBM traffic ~= x read (205MB) + out write (205MB).

typedef __attribute__((ext_vector_type(8))) short bf16x8;
typedef __attribute__((ext_vector_type(4))) float f32x4;

__device__ __forceinline__ unsigned short f2bf(float f) {
    unsigned u = __float_as_uint(f);
    u += 0x7fffu + ((u >> 16) & 1u);   // RNE
    return (unsigned short)(u >> 16);
}
__device__ __forceinline__ unsigned pk2(float a, float b) {
    return (unsigned)f2bf(a) | ((unsigned)f2bf(b) << 16);
}
__device__ __forceinline__ void gl2lds16(const void* gptr, void* lptr) {
    __builtin_amdgcn_global_load_lds(
        (const __attribute__((address_space(1))) unsigned int*)gptr,
        (__attribute__((address_space(3))) unsigned int*)lptr, 16, 0, 0);
}

// ---- K0: weights fp32 -> bf16, transposed to [feat][k] (B^T) layout ----
__global__ void k_prep(const float* __restrict__ qkv_w, const float* __restrict__ proj_w,
                       short* __restrict__ Wqkv_t, short* __restrict__ Wproj_t) {
    int tid = blockIdx.x * 256 + threadIdx.x;   // 262144 total
    if (tid < 196608) {                          // 768*256
        int nn = tid >> 8, kk = tid & 255;
        Wqkv_t[tid] = (short)f2bf(qkv_w[kk * 768 + nn]);
    } else {
        int t2 = tid - 196608;                   // 256*256
        int nn = t2 >> 8, kk = t2 & 255;
        Wproj_t[t2] = (short)f2bf(proj_w[kk * 256 + nn]);
    }
}

// LDS map (shorts). Total 75776 shorts (151552 B) + rpbs 5408 B = 156960 B.
//   QS  @ 0      [8h][64tok][32d]  (chunk-swz)  -> recycled as AO after attn
//   KS  @ 16384  [8h][64tok][32d]  (chunk-swz)
//   VT  @ 32768  [8h][32d][72tok]  (stride-72, V transposed)
//   XS  @ 51200  [64tok][256k]     (chunk-swz)  } union: PL @51200 [8w][16n][72m]
//   WS  @ 67584  2 x [128][32] weight dbuf (K1-style swz), disjoint from PL
#define QS_OFF 0
#define KS_OFF 16384
#define VT_OFF 32768
#define XS_OFF 51200
#define PL_OFF 51200
#define WS_OFF 67584

__global__ __launch_bounds__(512, 1) void k_fused(
        const float* __restrict__ x, const short* __restrict__ Wq,
        const short* __restrict__ Wp, const float* __restrict__ qkv_b,
        const float* __restrict__ rpb, const float* __restrict__ proj_b,
        float* __restrict__ out) {
    __shared__ __align__(16) short smem[75776];
    __shared__ float rpbs[1352];

    const int b = blockIdx.x;
    const int t = threadIdx.x;
    const int w = t >> 6, lane = t & 63;
    const int l15 = lane & 15, g = lane >> 4;
    const int wr = w >> 1, wc = w & 1;            // 4 feat-bands x 2 tok-bands
    const int cs8 = (l15 >> 1) & 3;               // chunk-swz field for 32-short rows
    const int swz = (g ^ cs8) << 3;               // swizzled frag chunk offset

    // weight staging: thread t covers granule t of a [128][32] tile
    const int srow = t >> 2;
    const int sseg = (t & 3) ^ ((t >> 3) & 3);    // inverse chunk swizzle on source

    f32x4 zero = {0.f, 0.f, 0.f, 0.f};

    // ---- phase 0: stage first W tile; copy rpb; x fp32 -> bf16 LDS ----
    gl2lds16(Wq + (size_t)srow * 256 + sseg * 8, &smem[WS_OFF + t * 8]);
    for (int i = t; i < 1352; i += 512) rpbs[i] = rpb[i];
    for (int i = 0; i < 4; i++) {
        int cid = t + i * 512;                    // 2048 granules = 64 tok x 32 chunks
        int tok = cid >> 5, c = cid & 31;
        uint4 w4 = make_uint4(0u, 0u, 0u, 0u);
        if (tok < 49) {
            const float4* s = (const float4*)(x + ((size_t)b * 49 + tok) * 256 + c * 8);
            float4 f0 = s[0], f1 = s[1];
            w4 = make_uint4(pk2(f0.x, f0.y), pk2(f0.z, f0.w),
                            pk2(f1.x, f1.y), pk2(f1.z, f1.w));
        }
        *(uint4*)&smem[XS_OFF + tok * 256 + ((c ^ (tok & 7)) << 3)] = w4;
    }
    __syncthreads();

    // ---- phase 1: QKV GEMM (6 fblk x 8 ks), dbuf weight stream ----
    int buf = 0;
    for (int fblk = 0; fblk < 6; fblk++) {
        f32x4 acc[2][2];
        for (int i = 0; i < 2; i++)
            for (int j = 0; j < 2; j++) acc[i][j] = zero;
        for (int ks = 0; ks < 8; ks++) {
            int st = fblk * 8 + ks;
            if (st < 47) {
                int nf = (st + 1) >> 3, nk = (st + 1) & 7;
                gl2lds16(Wq + (size_t)(nf * 128 + srow) * 256 + nk * 32 + sseg * 8,
                         &smem[WS_OFF + (buf ^ 1) * 4096 + t * 8]);
            }
            const short* Wb = &smem[WS_OFF + buf * 4096];
            bf16x8 af0 = *(const bf16x8*)&Wb[(wr * 32 + l15) * 32 + swz];
            bf16x8 af1 = *(const bf16x8*)&Wb[(wr * 32 + 16 + l15) * 32 + swz];
            int tok0 = wc * 32 + l15;
            int xsl = (((ks << 2) + g) ^ (l15 & 7)) << 3;
            bf16x8 bf0 = *(const bf16x8*)&smem[XS_OFF + tok0 * 256 + xsl];
            bf16x8 bf1 = *(const bf16x8*)&smem[XS_OFF + (tok0 + 16) * 256 + xsl];
            acc[0][0] = __builtin_amdgcn_mfma_f32_16x16x32_bf16(af0, bf0, acc[0][0], 0, 0, 0);
            acc[0][1] = __builtin_amdgcn_mfma_f32_16x16x32_bf16(af0, bf1, acc[0][1], 0, 0, 0);
            acc[1][0] = __builtin_amdgcn_mfma_f32_16x16x32_bf16(af1, bf0, acc[1][0], 0, 0, 0);
            acc[1][1] = __builtin_amdgcn_mfma_f32_16x16x32_bf16(af1, bf1, acc[1][1], 0, 0, 0);
            __syncthreads();
            buf ^= 1;
        }
        // epilogue: scatter q,k -> QS/KS (chunk-swz), v -> VT (transposed)
        for (int i2 = 0; i2 < 2; i2++) {
            int f = fblk * 128 + wr * 32 + i2 * 16 + g * 4;
            int part = f >> 8, h = (f >> 5) & 7, d0 = f & 31;
            float4 bv = *(const float4*)&qkv_b[f];
            for (int j2 = 0; j2 < 2; j2++) {
                int tok = wc * 32 + j2 * 16 + l15;
                float v0 = acc[i2][j2][0] + bv.x, v1 = acc[i2][j2][1] + bv.y;
                float v2 = acc[i2][j2][2] + bv.z, v3 = acc[i2][j2][3] + bv.w;
                if (part < 2) {
                    int bo = (part ? KS_OFF : QS_OFF) + h * 2048 + tok * 32;
                    unsigned* dst = (unsigned*)&smem[bo + (((d0 >> 3) ^ cs8) << 3) + (d0 & 7)];
                    dst[0] = pk2(v0, v1);
                    dst[1] = pk2(v2, v3);
                } else {
                    short* vt = &smem[VT_OFF + h * 2304 + tok];
                    vt[(d0 + 0) * 72] = (short)f2bf(v0);
                    vt[(d0 + 1) * 72] = (short)f2bf(v1);
                    vt[(d0 + 2) * 72] = (short)f2bf(v2);
                    vt[(d0 + 3) * 72] = (short)f2bf(v3);
                }
            }
        }
    }
    __syncthreads();   // all Q/K/V epilogue writes visible

    // ---- phase 2: attention, wave w = head w ----
    {
        const int h = w;
        const short* Kb = &smem[KS_OFF + h * 2048];
        const short* Qb = &smem[QS_OFF + h * 2048];
        bf16x8 ka[4], qb4[4], va[2][2];
        for (int mt = 0; mt < 4; mt++)
            ka[mt] = *(const bf16x8*)&Kb[(mt * 16 + l15) * 32 + swz];
        for (int nt = 0; nt < 4; nt++)
            qb4[nt] = *(const bf16x8*)&Qb[(nt * 16 + l15) * 32 + swz];
        for (int dt = 0; dt < 2; dt++)
            for (int kk = 0; kk < 2; kk++)
                va[dt][kk] = *(const bf16x8*)&smem[VT_OFF + h * 2304 +
                                                  (dt * 16 + l15) * 72 + kk * 32 + g * 8];
        short* Plw = &smem[PL_OFF + w * 1152];    // per-wave [16n][72m]
        short* AOw = &smem[QS_OFF + h * 2048];    // recycle Q region as aout [h][tok][32]
        const float scale = 0.17677669529663687f; // 1/sqrt(32)

        for (int nt = 0; nt < 4; nt++) {
            f32x4 s4[4];
            for (int mt = 0; mt < 4; mt++)
                s4[mt] = __builtin_amdgcn_mfma_f32_16x16x32_bf16(ka[mt], qb4[nt], zero, 0, 0, 0);
            int n = nt * 16 + l15;
            int ni = n / 7;
            int an = 13 * ni + (n - 7 * ni) + 84;
            for (int mt = 0; mt < 4; mt++)
                for (int r = 0; r < 4; r++) {
                    int m = mt * 16 + g * 4 + r;
                    int mi = m / 7;
                    int idx = an - (13 * mi + (m - 7 * mi));
                    idx = idx < 0 ? 0 : (idx > 168 ? 168 : idx);
                    float val = s4[mt][r] * scale + rpbs[idx * 8 + h];
                    s4[mt][r] = (m < 49) ? val : -1e30f;
                }
            float tmax = -1e30f;
            for (int mt = 0; mt < 4; mt++)
                for (int r = 0; r < 4; r++) tmax = fmaxf(tmax, s4[mt][r]);
            tmax = fmaxf(tmax, __shfl_xor(tmax, 16));
            tmax = fmaxf(tmax, __shfl_xor(tmax, 32));
            float rsum = 0.f;
            for (int mt = 0; mt < 4; mt++)
                for (int r = 0; r < 4; r++) {
                    float e = __expf(s4[mt][r] - tmax);
                    s4[mt][r] = e;
                    rsum += e;
                }
            rsum += __shfl_xor(rsum, 16);
            rsum += __shfl_xor(rsum, 32);

            for (int mt = 0; mt < 4; mt++) {
                unsigned* dst = (unsigned*)&Plw[l15 * 72 + mt * 16 + g * 4];
                dst[0] = pk2(s4[mt][0], s4[mt][1]);
                dst[1] = pk2(s4[mt][2], s4[mt][3]);
            }
            __syncthreads();   // uniform: order Pl cross-lane writes before reads

            bf16x8 pb0 = *(const bf16x8*)&Plw[l15 * 72 + g * 8];
            bf16x8 pb1 = *(const bf16x8*)&Plw[l15 * 72 + 32 + g * 8];
            f32x4 o0 = __builtin_amdgcn_mfma_f32_16x16x32_bf16(va[0][0], pb0, zero, 0, 0, 0);
            o0 = __builtin_amdgcn_mfma_f32_16x16x32_bf16(va[0][1], pb1, o0, 0, 0, 0);
            f32x4 o1 = __builtin_amdgcn_mfma_f32_16x16x32_bf16(va[1][0], pb0, zero, 0, 0, 0);
            o1 = __builtin_amdgcn_mfma_f32_16x16x32_bf16(va[1][1], pb1, o1, 0, 0, 0);
            float inv = 1.f / rsum;
            {
                int d0 = g * 4;            // dt = 0
                unsigned* dst = (unsigned*)&AOw[n * 32 + (((d0 >> 3) ^ cs8) << 3) + (d0 & 7)];
                dst[0] = pk2(o0[0] * inv, o0[1] * inv);
                dst[1] = pk2(o0[2] * inv, o0[3] * inv);
            }
            {
                int d0 = 16 + g * 4;       // dt = 1
                unsigned* dst = (unsigned*)&AOw[n * 32 + (((d0 >> 3) ^ cs8) << 3) + (d0 & 7)];
                dst[0] = pk2(o1[0] * inv, o1[1] * inv);
                dst[1] = pk2(o1[2] * inv, o1[3] * inv);
            }
            __syncthreads();   // uniform: protect Pl reads before next nt's writes
        }
    }

    // ---- phase 3: proj GEMM (2 foblk x 8 ks) ----
    buf = 0;
    gl2lds16(Wp + (size_t)srow * 256 + sseg * 8, &smem[WS_OFF + t * 8]);  // WS disjoint from PL
    __syncthreads();   // aout visible everywhere + stage0 drained
    for (int foblk = 0; foblk < 2; foblk++) {
        f32x4 acc[2][2];
        for (int i = 0; i < 2; i++)
            for (int j = 0; j < 2; j++) acc[i][j] = zero;
        for (int ks = 0; ks < 8; ks++) {
            int st = foblk * 8 + ks;
            if (st < 15) {
                int nf = (st + 1) >> 3, nk = (st + 1) & 7;
                gl2lds16(Wp + (size_t)(nf * 128 + srow) * 256 + nk * 32 + sseg * 8,
                         &smem[WS_OFF + (buf ^ 1) * 4096 + t * 8]);
            }
            const short* Wb = &smem[WS_OFF + buf * 4096];
            bf16x8 af0 = *(const bf16x8*)&Wb[(wr * 32 + l15) * 32 + swz];
            bf16x8 af1 = *(const bf16x8*)&Wb[(wr * 32 + 16 + l15) * 32 + swz];
            int tok0 = wc * 32 + l15;
            bf16x8 bf0 = *(const bf16x8*)&smem[QS_OFF + ks * 2048 + tok0 * 32 + swz];
            bf16x8 bf1 = *(const bf16x8*)&smem[QS_OFF + ks * 2048 + (tok0 + 16) * 32 + swz];
            acc[0][0] = __builtin_amdgcn_mfma_f32_16x16x32_bf16(af0, bf0, acc[0][0], 0, 0, 0);
            acc[0][1] = __builtin_amdgcn_mfma_f32_16x16x32_bf16(af0, bf1, acc[0][1], 0, 0, 0);
            acc[1][0] = __builtin_amdgcn_mfma_f32_16x16x32_bf16(af1, bf0, acc[1][0], 0, 0, 0);
            acc[1][1] = __builtin_amdgcn_mfma_f32_16x16x32_bf16(af1, bf1, acc[1][1], 0, 0, 0);
            __syncthreads();
            buf ^= 1;
        }
        for (int i2 = 0; i2 < 2; i2++) {
            int fo = foblk * 128 + wr * 32 + i2 * 16 + g * 4;
            float4 bv = *(const float4*)&proj_b[fo];
            for (int j2 = 0; j2 < 2; j2++) {
                int tok = wc * 32 + j2 * 16 + l15;
                if (tok < 49) {
                    float4 val = make_float4(acc[i2][j2][0] + bv.x, acc[i2][j2][1] + bv.y,
                                             acc[i2][j2][2] + bv.z, acc[i2][j2][3] + bv.w);
                    *(float4*)&out[((size_t)b * 49 + tok) * 256 + fo] = val;
                }
            }
        }
    }
}

extern "C" void kernel_launch(void* const* d_in, const int* in_sizes, int n_in,
                              void* d_out, int out_size, void* d_ws, size_t ws_size,
                              hipStream_t stream) {
    const float* x      = (const float*)d_in[0];
    const float* qkv_w  = (const float*)d_in[1];
    const float* qkv_b  = (const float*)d_in[2];
    const float* rpb    = (const float*)d_in[3];
    const float* proj_w = (const float*)d_in[4];
    const float* proj_b = (const float*)d_in[5];
    float* out = (float*)d_out;

    // ws (shorts): Wqkv_t[768*256] | Wproj_t[256*256]
    short* Wqkv_t  = (short*)d_ws;
    short* Wproj_t = Wqkv_t + 768 * 256;
    if (ws_size < 524288ull) return;

    k_prep<<<1024, 256, 0, stream>>>(qkv_w, proj_w, Wqkv_t, Wproj_t);
    k_fused<<<4096, 512, 0, stream>>>(x, Wqkv_t, Wproj_t, qkv_b, rpb, proj_b, out);
}

// Round 3
// 679.911 us; speedup vs baseline: 1.3987x; 1.3987x over previous
//
#include <hip/hip_runtime.h>
#include <stdint.h>

// Window attention, Swin-style. B=4096 windows, N=49, C=256, NH=8, D=32.
// FULLY FUSED v3: one block per window (512 thr, 8 waves), wave w owns head w.
// Weights are loaded as MFMA fragments DIRECTLY from L2 into registers (no LDS
// staging, no K-loop barriers). Per-block barriers: 2 total.
// HBM traffic ~= x read (205MB) + out write (205MB); weights stream from L2.

typedef __attribute__((ext_vector_type(8))) short bf16x8;
typedef __attribute__((ext_vector_type(4))) float f32x4;

__device__ __forceinline__ unsigned short f2bf(float f) {
    unsigned u = __float_as_uint(f);
    u += 0x7fffu + ((u >> 16) & 1u);   // RNE
    return (unsigned short)(u >> 16);
}
__device__ __forceinline__ unsigned pk2(float a, float b) {
    return (unsigned)f2bf(a) | ((unsigned)f2bf(b) << 16);
}

// ---- K0: weights fp32 -> bf16, transposed to [feat][k] (B^T) layout ----
__global__ void k_prep(const float* __restrict__ qkv_w, const float* __restrict__ proj_w,
                       short* __restrict__ Wqkv_t, short* __restrict__ Wproj_t) {
    int tid = blockIdx.x * 256 + threadIdx.x;   // 262144 total
    if (tid < 196608) {                          // 768*256
        int nn = tid >> 8, kk = tid & 255;
        Wqkv_t[tid] = (short)f2bf(qkv_w[kk * 768 + nn]);
    } else {
        int t2 = tid - 196608;                   // 256*256
        int nn = t2 >> 8, kk = t2 & 255;
        Wproj_t[t2] = (short)f2bf(proj_w[kk * 256 + nn]);
    }
}

// LDS map (shorts). Total 76800 shorts (153600 B) + rpbs 5408 B = 159008 B.
//   XS @ 0      [64tok][256k]    (chunk-swz)        32 KB  (dead after phase 1)
//   QS @ 16384  [8h][64tok][32d] (chunk-swz)        32 KB  (recycled as AO)
//   KS @ 32768  [8h][64tok][32d] (chunk-swz)        32 KB
//   VT @ 49152  [8h][32d][72tok] (V transposed)     36 KB
//   PL @ 67584  [8w][16n][72m]   per-wave P scratch 18 KB
#define XS_OFF 0
#define QS_OFF 16384
#define KS_OFF 32768
#define VT_OFF 49152
#define PL_OFF 67584

__global__ __launch_bounds__(512, 1) void k_fused(
        const float* __restrict__ x, const short* __restrict__ Wq,
        const short* __restrict__ Wp, const float* __restrict__ qkv_b,
        const float* __restrict__ rpb, const float* __restrict__ proj_b,
        float* __restrict__ out) {
    __shared__ __align__(16) short smem[76800];
    __shared__ float rpbs[1352];

    const int b = blockIdx.x;
    const int t = threadIdx.x;
    const int w = t >> 6, lane = t & 63;
    const int l15 = lane & 15, g = lane >> 4;
    const int cs8 = (l15 >> 1) & 3;               // chunk-swz field for 32-short rows
    const int swz = (g ^ cs8) << 3;               // swizzled frag chunk offset

    f32x4 zero = {0.f, 0.f, 0.f, 0.f};

    // ---- phase 0: rpb -> LDS; x fp32 -> bf16 -> XS (chunk-swz), zero-pad ----
    for (int i = t; i < 1352; i += 512) rpbs[i] = rpb[i];
    #pragma unroll
    for (int i = 0; i < 4; i++) {
        int cid = t + i * 512;                    // 2048 granules = 64 tok x 32 chunks
        int tok = cid >> 5, c = cid & 31;
        uint4 w4 = make_uint4(0u, 0u, 0u, 0u);
        if (tok < 49) {
            const float4* s = (const float4*)(x + ((size_t)b * 49 + tok) * 256 + c * 8);
            float4 f0 = s[0], f1 = s[1];
            w4 = make_uint4(pk2(f0.x, f0.y), pk2(f0.z, f0.w),
                            pk2(f1.x, f1.y), pk2(f1.z, f1.w));
        }
        *(uint4*)&smem[XS_OFF + tok * 256 + ((c ^ (tok & 7)) << 3)] = w4;
    }
    __syncthreads();   // barrier #1: XS + rpbs visible

    // ---- phase 1: QKV GEMM. Wave w computes Q,K,V of head w (96 feats x 64 tok).
    //      A-frags (weights) straight from L2; B-frags from XS. No barriers. ----
    {
        f32x4 acc[6][4];                          // [p*2+it][tok quadrant]
        #pragma unroll
        for (int i = 0; i < 6; i++)
            #pragma unroll
            for (int j = 0; j < 4; j++) acc[i][j] = zero;

        const short* wbase = Wq + (size_t)(w * 32 + l15) * 256 + g * 8;
        #pragma unroll
        for (int ks = 0; ks < 8; ks++) {
            bf16x8 af[6], bfj[4];
            #pragma unroll
            for (int p = 0; p < 3; p++)
                #pragma unroll
                for (int it = 0; it < 2; it++)
                    af[p * 2 + it] = *(const bf16x8*)(wbase + p * 65536 + it * 4096 + ks * 32);
            int xsl = (((ks << 2) + g) ^ (l15 & 7)) << 3;
            #pragma unroll
            for (int j = 0; j < 4; j++)
                bfj[j] = *(const bf16x8*)&smem[XS_OFF + (j * 16 + l15) * 256 + xsl];
            #pragma unroll
            for (int i = 0; i < 6; i++)
                #pragma unroll
                for (int j = 0; j < 4; j++)
                    acc[i][j] = __builtin_amdgcn_mfma_f32_16x16x32_bf16(
                        af[i], bfj[j], acc[i][j], 0, 0, 0);
        }
        // epilogue (wave-local): Q,K -> QS/KS[h=w] chunk-swz; V -> VT[h=w] transposed
        #pragma unroll
        for (int p = 0; p < 2; p++) {
            int base = (p ? KS_OFF : QS_OFF) + w * 2048;
            #pragma unroll
            for (int it = 0; it < 2; it++) {
                int d0 = it * 16 + g * 4;
                float4 bv = *(const float4*)&qkv_b[p * 256 + w * 32 + d0];
                #pragma unroll
                for (int j = 0; j < 4; j++) {
                    int tok = j * 16 + l15;
                    f32x4 a = acc[p * 2 + it][j];
                    unsigned* dst = (unsigned*)&smem[base + tok * 32 +
                                                     (((d0 >> 3) ^ cs8) << 3) + (d0 & 7)];
                    dst[0] = pk2(a[0] + bv.x, a[1] + bv.y);
                    dst[1] = pk2(a[2] + bv.z, a[3] + bv.w);
                }
            }
        }
        {
            short* vt = &smem[VT_OFF + w * 2304];
            #pragma unroll
            for (int it = 0; it < 2; it++) {
                int d0 = it * 16 + g * 4;
                float4 bv = *(const float4*)&qkv_b[512 + w * 32 + d0];
                #pragma unroll
                for (int j = 0; j < 4; j++) {
                    int tok = j * 16 + l15;
                    f32x4 a = acc[4 + it][j];
                    vt[(d0 + 0) * 72 + tok] = (short)f2bf(a[0] + bv.x);
                    vt[(d0 + 1) * 72 + tok] = (short)f2bf(a[1] + bv.y);
                    vt[(d0 + 2) * 72 + tok] = (short)f2bf(a[2] + bv.z);
                    vt[(d0 + 3) * 72 + tok] = (short)f2bf(a[3] + bv.w);
                }
            }
        }
    }

    // ---- phase 2: attention, fully wave-local (head h = w), no barriers ----
    {
        const int h = w;
        const short* Kb = &smem[KS_OFF + h * 2048];
        const short* Qb = &smem[QS_OFF + h * 2048];
        bf16x8 ka[4], qb4[4], va[2][2];
        #pragma unroll
        for (int mt = 0; mt < 4; mt++)
            ka[mt] = *(const bf16x8*)&Kb[(mt * 16 + l15) * 32 + swz];
        #pragma unroll
        for (int nt = 0; nt < 4; nt++)
            qb4[nt] = *(const bf16x8*)&Qb[(nt * 16 + l15) * 32 + swz];
        #pragma unroll
        for (int dt = 0; dt < 2; dt++)
            #pragma unroll
            for (int kk = 0; kk < 2; kk++)
                va[dt][kk] = *(const bf16x8*)&smem[VT_OFF + h * 2304 +
                                                  (dt * 16 + l15) * 72 + kk * 32 + g * 8];
        short* Plw = &smem[PL_OFF + w * 1152];    // per-wave [16n][72m]
        short* AOw = &smem[QS_OFF + h * 2048];    // recycle Q region as AO [tok][32] swz
        const float scale = 0.17677669529663687f; // 1/sqrt(32)

        #pragma unroll
        for (int nt = 0; nt < 4; nt++) {
            f32x4 s4[4];
            #pragma unroll
            for (int mt = 0; mt < 4; mt++)
                s4[mt] = __builtin_amdgcn_mfma_f32_16x16x32_bf16(ka[mt], qb4[nt], zero, 0, 0, 0);
            int n = nt * 16 + l15;
            int ni = n / 7;
            int an = 13 * ni + (n - 7 * ni) + 84;
            #pragma unroll
            for (int mt = 0; mt < 4; mt++)
                #pragma unroll
                for (int r = 0; r < 4; r++) {
                    int m = mt * 16 + g * 4 + r;
                    int mi = m / 7;
                    int idx = an - (13 * mi + (m - 7 * mi));
                    idx = idx < 0 ? 0 : (idx > 168 ? 168 : idx);
                    float val = s4[mt][r] * scale + rpbs[idx * 8 + h];
                    s4[mt][r] = (m < 49) ? val : -1e30f;
                }
            float tmax = -1e30f;
            #pragma unroll
            for (int mt = 0; mt < 4; mt++)
                #pragma unroll
                for (int r = 0; r < 4; r++) tmax = fmaxf(tmax, s4[mt][r]);
            tmax = fmaxf(tmax, __shfl_xor(tmax, 16));
            tmax = fmaxf(tmax, __shfl_xor(tmax, 32));
            float rsum = 0.f;
            #pragma unroll
            for (int mt = 0; mt < 4; mt++)
                #pragma unroll
                for (int r = 0; r < 4; r++) {
                    float e = __expf(s4[mt][r] - tmax);
                    s4[mt][r] = e;
                    rsum += e;
                }
            rsum += __shfl_xor(rsum, 16);
            rsum += __shfl_xor(rsum, 32);

            // P (unnormalized) -> Plw[n'][m]; wave-local, in-order LDS => no barrier
            #pragma unroll
            for (int mt = 0; mt < 4; mt++) {
                unsigned* dst = (unsigned*)&Plw[l15 * 72 + mt * 16 + g * 4];
                dst[0] = pk2(s4[mt][0], s4[mt][1]);
                dst[1] = pk2(s4[mt][2], s4[mt][3]);
            }
            bf16x8 pb0 = *(const bf16x8*)&Plw[l15 * 72 + g * 8];
            bf16x8 pb1 = *(const bf16x8*)&Plw[l15 * 72 + 32 + g * 8];
            f32x4 o0 = __builtin_amdgcn_mfma_f32_16x16x32_bf16(va[0][0], pb0, zero, 0, 0, 0);
            o0 = __builtin_amdgcn_mfma_f32_16x16x32_bf16(va[0][1], pb1, o0, 0, 0, 0);
            f32x4 o1 = __builtin_amdgcn_mfma_f32_16x16x32_bf16(va[1][0], pb0, zero, 0, 0, 0);
            o1 = __builtin_amdgcn_mfma_f32_16x16x32_bf16(va[1][1], pb1, o1, 0, 0, 0);
            float inv = 1.f / rsum;
            {
                int d0 = g * 4;            // dt = 0
                unsigned* dst = (unsigned*)&AOw[n * 32 + (((d0 >> 3) ^ cs8) << 3) + (d0 & 7)];
                dst[0] = pk2(o0[0] * inv, o0[1] * inv);
                dst[1] = pk2(o0[2] * inv, o0[3] * inv);
            }
            {
                int d0 = 16 + g * 4;       // dt = 1
                unsigned* dst = (unsigned*)&AOw[n * 32 + (((d0 >> 3) ^ cs8) << 3) + (d0 & 7)];
                dst[0] = pk2(o1[0] * inv, o1[1] * inv);
                dst[1] = pk2(o1[2] * inv, o1[3] * inv);
            }
        }
    }
    __syncthreads();   // barrier #2: all heads' AO visible for proj

    // ---- phase 3: proj GEMM. Wave w computes out-feats [w*32, w*32+32).
    //      A-frags (Wp) from L2; B-frags from AO (k-step ks == head ks). ----
    {
        f32x4 acc2[2][4];
        #pragma unroll
        for (int i = 0; i < 2; i++)
            #pragma unroll
            for (int j = 0; j < 4; j++) acc2[i][j] = zero;

        const short* pbase = Wp + (size_t)(w * 32 + l15) * 256 + g * 8;
        #pragma unroll
        for (int ks = 0; ks < 8; ks++) {
            bf16x8 af2[2], bf2[4];
            af2[0] = *(const bf16x8*)(pbase + ks * 32);
            af2[1] = *(const bf16x8*)(pbase + 4096 + ks * 32);
            #pragma unroll
            for (int j = 0; j < 4; j++)
                bf2[j] = *(const bf16x8*)&smem[QS_OFF + ks * 2048 + (j * 16 + l15) * 32 + swz];
            #pragma unroll
            for (int i = 0; i < 2; i++)
                #pragma unroll
                for (int j = 0; j < 4; j++)
                    acc2[i][j] = __builtin_amdgcn_mfma_f32_16x16x32_bf16(
                        af2[i], bf2[j], acc2[i][j], 0, 0, 0);
        }
        #pragma unroll
        for (int it = 0; it < 2; it++) {
            int fo = w * 32 + it * 16 + g * 4;
            float4 bv = *(const float4*)&proj_b[fo];
            #pragma unroll
            for (int j = 0; j < 4; j++) {
                int tok = j * 16 + l15;
                if (tok < 49) {
                    f32x4 a = acc2[it][j];
                    float4 val = make_float4(a[0] + bv.x, a[1] + bv.y,
                                             a[2] + bv.z, a[3] + bv.w);
                    *(float4*)&out[((size_t)b * 49 + tok) * 256 + fo] = val;
                }
            }
        }
    }
}

extern "C" void kernel_launch(void* const* d_in, const int* in_sizes, int n_in,
                              void* d_out, int out_size, void* d_ws, size_t ws_size,
                              hipStream_t stream) {
    const float* x      = (const float*)d_in[0];
    const float* qkv_w  = (const float*)d_in[1];
    const float* qkv_b  = (const float*)d_in[2];
    const float* rpb    = (const float*)d_in[3];
    const float* proj_w = (const float*)d_in[4];
    const float* proj_b = (const float*)d_in[5];
    float* out = (float*)d_out;

    // ws (shorts): Wqkv_t[768*256] | Wproj_t[256*256]
    short* Wqkv_t  = (short*)d_ws;
    short* Wproj_t = Wqkv_t + 768 * 256;
    if (ws_size < 524288ull) return;

    k_prep<<<1024, 256, 0, stream>>>(qkv_w, proj_w, Wqkv_t, Wproj_t);
    k_fused<<<4096, 512, 0, stream>>>(x, Wqkv_t, Wproj_t, qkv_b, rpb, proj_b, out);
}